// Round 2
// baseline (609.716 us; speedup 1.0000x reference)
//
#include <hip/hip_runtime.h>
#include <cstdint>
#include <cstddef>

// ---------------------------------------------------------------------------
// GraphAttentionHead: out = elu(softmax(mask(LeakyReLU(mu_i + xi_j))) @ h)
// Round 2: barrier-free attention K-loop.
//   - wave = 16 i-rows x 256 out-cols, j-window 2048 (j-split 4)
//   - A-frag (softmax weights) built in registers from adj + LDS xi
//   - B-frag read directly from global ht (L1/L2 resident, 4 MB)
//   - no __syncthreads in the hot loop -> compiler pipelines adj loads
//   - j-split partials combined via fp32 global atomicAdd, finalize kernel
// ---------------------------------------------------------------------------

#define NN 8192
#define DIN 512
#define DOUT 256

typedef __attribute__((ext_vector_type(8))) short short8;   // 8 bf16 = 4 VGPRs
typedef __attribute__((ext_vector_type(4))) float floatx4;  // MFMA acc

using uint_as1 = __attribute__((address_space(1))) unsigned int;
using uint_as3 = __attribute__((address_space(3))) unsigned int;

__device__ __forceinline__ void gld_lds16(const void* g, void* l) {
  __builtin_amdgcn_global_load_lds((const uint_as1*)g, (uint_as3*)l, 16, 0, 0);
}

__device__ __forceinline__ unsigned short f2b(float f) {  // fp32 -> bf16 RNE (finite)
  unsigned u = __float_as_uint(f);
  u += 0x7fffu + ((u >> 16) & 1u);
  return (unsigned short)(u >> 16);
}
__device__ __forceinline__ float b2f(short s) {
  return __uint_as_float(((unsigned)(unsigned short)s) << 16);
}

// --------------------------- K0a: features -> bf16 -------------------------
__global__ void k_cvt_features(const float* __restrict__ f, unsigned short* __restrict__ fb) {
  int tid = blockIdx.x * 256 + threadIdx.x;
  float4 v = ((const float4*)f)[tid];
  ushort4 o = {f2b(v.x), f2b(v.y), f2b(v.z), f2b(v.w)};
  *(ushort4*)&fb[tid * 4] = o;
}

// ------------------- K0b: W_phi [512][256] -> Wt bf16 [256][512] ------------
__global__ void k_prep_wt(const float* __restrict__ w, unsigned short* __restrict__ wt) {
  int tid = blockIdx.x * 256 + threadIdx.x;
  int n = tid >> 9, k = tid & 511;
  wt[n * 512 + k] = f2b(w[k * 256 + n]);
}

// ----------------- K0c: p_mu = W_phi @ w_mu, p_xi = W_phi @ w_xi ------------
__global__ void k_prep_p(const float* __restrict__ w, const float* __restrict__ wmu,
                         const float* __restrict__ wxi, float* __restrict__ pmu,
                         float* __restrict__ pxi) {
  int tid = blockIdx.x * 256 + threadIdx.x;
  int k = tid >> 2, seg = tid & 3;
  float sm = 0.f, sx = 0.f;
  int base = k * 256 + seg * 64;
#pragma unroll
  for (int c = 0; c < 64; c += 4) {
    float4 wv = *(const float4*)&w[base + c];
    float4 mv = *(const float4*)&wmu[seg * 64 + c];
    float4 xv = *(const float4*)&wxi[seg * 64 + c];
    sm += wv.x * mv.x + wv.y * mv.y + wv.z * mv.z + wv.w * mv.w;
    sx += wv.x * xv.x + wv.y * xv.y + wv.z * xv.z + wv.w * xv.w;
  }
  sm += __shfl_xor(sm, 1); sm += __shfl_xor(sm, 2);
  sx += __shfl_xor(sx, 1); sx += __shfl_xor(sx, 2);
  if (seg == 0) { pmu[k] = sm; pxi[k] = sx; }
}

// ----------------- K2: mu/xi = features_bf @ p_mu / p_xi (wave per row) -----
__global__ void k_mu_xi(const unsigned short* __restrict__ fb, const float* __restrict__ pmu,
                        const float* __restrict__ pxi, float* __restrict__ mu,
                        float* __restrict__ xi) {
  int w = threadIdx.x >> 6, l = threadIdx.x & 63;
  int i = blockIdx.x * 4 + w;
  short8 fv = *(const short8*)&fb[i * 512 + l * 8];
  float m = 0.f, x = 0.f;
#pragma unroll
  for (int c = 0; c < 8; ++c) {
    float fvf = b2f(fv[c]);
    m = fmaf(fvf, pmu[l * 8 + c], m);
    x = fmaf(fvf, pxi[l * 8 + c], x);
  }
#pragma unroll
  for (int off = 32; off > 0; off >>= 1) {
    m += __shfl_xor(m, off);
    x += __shfl_xor(x, off);
  }
  if (l == 0) { mu[i] = m; xi[i] = x; }
}

// ------------- K1: h_t[n][m] = (features @ W_phi)^T, bf16 MFMA --------------
__global__ __launch_bounds__(256, 2) void k_gemm1(const unsigned short* __restrict__ fb,
                                                  const unsigned short* __restrict__ wt,
                                                  unsigned short* __restrict__ ht) {
  __shared__ __align__(16) unsigned short As[64 * 64];
  __shared__ __align__(16) unsigned short Bs[128 * 64];
  int t = threadIdx.x, w = t >> 6, l = t & 63;
  int bm = blockIdx.x >> 1, bn = blockIdx.x & 1;
  int m0 = bm * 64, n0 = bn * 128;
  int lr = l >> 3, lg = l & 7, g = lg ^ lr;
  int kg = l >> 4, ln = l & 15;
  floatx4 zero = {0.f, 0.f, 0.f, 0.f};
  floatx4 acc[4][2];
#pragma unroll
  for (int mf = 0; mf < 4; ++mf)
#pragma unroll
    for (int nf = 0; nf < 2; ++nf) acc[mf][nf] = zero;

  for (int it = 0; it < 8; ++it) {
    int k0 = it * 64;
#pragma unroll
    for (int q = 0; q < 2; ++q) {
      int row = w * 16 + q * 8 + lr;
      const void* gp = fb + (size_t)(m0 + row) * 512 + k0 + g * 8;
      int lb = __builtin_amdgcn_readfirstlane((w * 16 + q * 8) * 64);
      gld_lds16(gp, &As[lb]);
    }
#pragma unroll
    for (int q = 0; q < 4; ++q) {
      int row = w * 32 + q * 8 + lr;
      const void* gp = wt + (size_t)(n0 + row) * 512 + k0 + g * 8;
      int lb = __builtin_amdgcn_readfirstlane((w * 32 + q * 8) * 64);
      gld_lds16(gp, &Bs[lb]);
    }
    __syncthreads();
#pragma unroll
    for (int ks = 0; ks < 2; ++ks) {
      int gg = ks * 4 + kg;
      int swz = (gg ^ (ln & 7)) * 8;
      short8 bfr[2];
#pragma unroll
      for (int nf = 0; nf < 2; ++nf)
        bfr[nf] = *(const short8*)&Bs[(w * 32 + nf * 16 + ln) * 64 + swz];
#pragma unroll
      for (int mf = 0; mf < 4; ++mf) {
        short8 afr = *(const short8*)&As[(mf * 16 + ln) * 64 + swz];
#pragma unroll
        for (int nf = 0; nf < 2; ++nf)
          acc[mf][nf] = __builtin_amdgcn_mfma_f32_16x16x32_bf16(afr, bfr[nf], acc[mf][nf], 0, 0, 0);
      }
    }
    __syncthreads();
  }
#pragma unroll
  for (int mf = 0; mf < 4; ++mf)
#pragma unroll
    for (int nf = 0; nf < 2; ++nf) {
      int ng = n0 + w * 32 + nf * 16 + ln;
      int mg = m0 + mf * 16 + kg * 4;
      ushort4 o = {f2b(acc[mf][nf][0]), f2b(acc[mf][nf][1]),
                   f2b(acc[mf][nf][2]), f2b(acc[mf][nf][3])};
      *(ushort4*)&ht[(size_t)ng * 8192 + mg] = o;
    }
}

// -------------------- K_zero: clear numerator + Z buffers -------------------
__global__ void k_zero(float* __restrict__ num, float* __restrict__ zbuf) {
  int b = blockIdx.x, t = threadIdx.x;
  if (b < 2048) {
    float4 z4 = {0.f, 0.f, 0.f, 0.f};
    *(float4*)&num[(b * 256 + t) * 4] = z4;
  } else {
    zbuf[(b - 2048) * 256 + t] = 0.f;
  }
}

// --------------------- K3: barrier-free masked attention --------------------
// grid 512 = 128 i-tiles x 4 j-splits; 4 waves; wave = 16 i x 256 n, j 2048.
// bj = blockIdx&3 so co-resident blocks (idx, idx+256) share a j-window.
__global__ __launch_bounds__(256, 2) void k_attn3(const int* __restrict__ adj,
                                                  const unsigned short* __restrict__ ht,
                                                  const float* __restrict__ mu,
                                                  const float* __restrict__ xi,
                                                  float* __restrict__ num,
                                                  float* __restrict__ zbuf) {
  __shared__ __align__(16) float xic[2048];   // xi * log2(e) for this j-window
  int t = threadIdx.x, w = t >> 6, l = t & 63;
  int ln = l & 15, kg = l >> 4;
  int bi = blockIdx.x >> 2, bj = blockIdx.x & 3;
  int i0 = bi * 64, jbase = bj * 2048;

#pragma unroll
  for (int c = 0; c < 2; ++c) {            // stage 2048 scaled xi into LDS
    int idx = t * 8 + c * 4;
    float4 v = *(const float4*)&xi[jbase + idx];
    v.x *= 1.44269504f; v.y *= 1.44269504f; v.z *= 1.44269504f; v.w *= 1.44269504f;
    *(float4*)&xic[idx] = v;
  }
  int irow = i0 + w * 16 + ln;
  float mu_c = mu[irow] * 1.44269504f;
  __syncthreads();                          // only barrier in the kernel

  floatx4 zero = {0.f, 0.f, 0.f, 0.f};
  floatx4 acc[16];
#pragma unroll
  for (int nf = 0; nf < 16; ++nf) acc[nf] = zero;

  // adj int4 pointer for this lane's row; lane covers j = jo + kg*8 + c (ks0)
  // and j = jo + 32 + kg*8 + c (ks1)
  const int4* ap = (const int4*)(adj + (size_t)irow * 8192 + jbase) + kg * 2;
  int4 a0 = ap[0], a1 = ap[1], b0 = ap[8], b1 = ap[9];
  const unsigned short* hrow = ht + (size_t)ln * 8192 + jbase + kg * 8;
  float zsum = 0.f;

  for (int it = 0; it < 32; ++it) {
    int jo = it * 64;
    int xb = jo + kg * 8;
    float4 x0  = *(const float4*)&xic[xb];
    float4 x0b = *(const float4*)&xic[xb + 4];
    float4 x1  = *(const float4*)&xic[xb + 32];
    float4 x1b = *(const float4*)&xic[xb + 36];

    int am[16] = {a0.x, a0.y, a0.z, a0.w, a1.x, a1.y, a1.z, a1.w,
                  b0.x, b0.y, b0.z, b0.w, b1.x, b1.y, b1.z, b1.w};
    float xv[16] = {x0.x, x0.y, x0.z, x0.w, x0b.x, x0b.y, x0b.z, x0b.w,
                    x1.x, x1.y, x1.z, x1.w, x1b.x, x1b.y, x1b.z, x1b.w};

    // prefetch next iteration's adjacency while we compute + MFMA
    int noff = (it < 31) ? (it + 1) * 16 : 0;
    a0 = ap[noff]; a1 = ap[noff + 1]; b0 = ap[noff + 8]; b1 = ap[noff + 9];

    float wv[16];
#pragma unroll
    for (int c = 0; c < 16; ++c) {
      float s = mu_c + xv[c];              // scaled score; LR commutes w/ scale
      s = fmaxf(s, 0.2f * s);
      float e = __builtin_amdgcn_exp2f(s);
      wv[c] = (am[c] != 0) ? e : 0.f;
      zsum += wv[c];
    }
    short8 afr0, afr1;
#pragma unroll
    for (int c = 0; c < 8; ++c) {
      afr0[c] = (short)f2b(wv[c]);
      afr1[c] = (short)f2b(wv[8 + c]);
    }

    const unsigned short* hp = hrow + jo;
#pragma unroll
    for (int nf = 0; nf < 16; ++nf) {
      const unsigned short* hn = hp + (size_t)nf * (16 * 8192);
      short8 bf0 = *(const short8*)hn;
      short8 bf1 = *(const short8*)(hn + 32);
      acc[nf] = __builtin_amdgcn_mfma_f32_16x16x32_bf16(afr0, bf0, acc[nf], 0, 0, 0);
      acc[nf] = __builtin_amdgcn_mfma_f32_16x16x32_bf16(afr1, bf1, acc[nf], 0, 0, 0);
    }
  }

  // Z: reduce the 4 lanes (ln, ln+16, ln+32, ln+48) covering row irow
  zsum += __shfl_xor(zsum, 16);
  zsum += __shfl_xor(zsum, 32);
  if (kg == 0) atomicAdd(&zbuf[irow], zsum);

  // numerator partial -> global atomic accumulate
#pragma unroll
  for (int nf = 0; nf < 16; ++nf) {
    int col = nf * 16 + ln;
#pragma unroll
    for (int r = 0; r < 4; ++r) {
      int row = i0 + w * 16 + kg * 4 + r;
      atomicAdd(&num[(size_t)row * 256 + col], acc[nf][r]);
    }
  }
}

// ------------------------- K4: finalize: /Z then ELU ------------------------
__global__ void k_final(const float* __restrict__ num, const float* __restrict__ zbuf,
                        float* __restrict__ out) {
  int tid = blockIdx.x * 256 + threadIdx.x;  // x4 floats
  int i = tid >> 6;
  float zi = 1.0f / zbuf[i];
  float4 v = *(const float4*)&num[tid * 4];
  v.x *= zi; v.y *= zi; v.z *= zi; v.w *= zi;
  v.x = (v.x > 0.f) ? v.x : (__builtin_amdgcn_exp2f(v.x * 1.44269504f) - 1.f);
  v.y = (v.y > 0.f) ? v.y : (__builtin_amdgcn_exp2f(v.y * 1.44269504f) - 1.f);
  v.z = (v.z > 0.f) ? v.z : (__builtin_amdgcn_exp2f(v.z * 1.44269504f) - 1.f);
  v.w = (v.w > 0.f) ? v.w : (__builtin_amdgcn_exp2f(v.w * 1.44269504f) - 1.f);
  *(float4*)&out[tid * 4] = v;
}

// ---------------------------------------------------------------------------
extern "C" void kernel_launch(void* const* d_in, const int* in_sizes, int n_in,
                              void* d_out, int out_size, void* d_ws, size_t ws_size,
                              hipStream_t stream) {
  const float* features = (const float*)d_in[0];
  const int* adjm = (const int*)d_in[1];
  const float* W_phi = (const float*)d_in[2];
  const float* w_mu = (const float*)d_in[3];
  const float* w_xi = (const float*)d_in[4];
  float* out = (float*)d_out;

  char* ws = (char*)d_ws;
  unsigned short* fb  = (unsigned short*)(ws + 0);         // 8192x512 bf16 = 8 MB
  unsigned short* ht  = (unsigned short*)(ws + 8388608);   // 256x8192 bf16 = 4 MB
  unsigned short* wt  = (unsigned short*)(ws + 12582912);  // 256x512 bf16 = 256 KB
  float* pmu = (float*)(ws + 12845056);                    // 512 f32
  float* pxi = (float*)(ws + 12847104);                    // 512 f32
  float* muv = (float*)(ws + 12849152);                    // 8192 f32
  float* xiv = (float*)(ws + 12881920);                    // 8192 f32
  // dead-region reuse (after k_gemm1): num over fb, zbuf over wt
  float* num  = (float*)(ws + 0);                          // 8192x256 f32 = 8 MB
  float* zbuf = (float*)(ws + 12582912);                   // 8192 f32

  k_cvt_features<<<4096, 256, 0, stream>>>(features, fb);
  k_prep_wt<<<512, 256, 0, stream>>>(W_phi, wt);
  k_prep_p<<<8, 256, 0, stream>>>(W_phi, w_mu, w_xi, pmu, pxi);
  k_mu_xi<<<2048, 256, 0, stream>>>(fb, pmu, pxi, muv, xiv);
  k_gemm1<<<256, 256, 0, stream>>>(fb, wt, ht);
  k_zero<<<2080, 256, 0, stream>>>(num, zbuf);
  k_attn3<<<512, 256, 0, stream>>>(adjm, ht, muv, xiv, num, zbuf);
  k_final<<<2048, 256, 0, stream>>>(num, zbuf, out);
}

// Round 3
// 476.166 us; speedup vs baseline: 1.2805x; 1.2805x over previous
//
#include <hip/hip_runtime.h>
#include <cstdint>
#include <cstddef>

// ---------------------------------------------------------------------------
// GraphAttentionHead: out = elu(softmax(mask(LeakyReLU(mu_i + xi_j))) @ h)
// Round 3: LDS-staged B with reuse x4 + register-built W tile, m97-style
// 2-barrier pipeline. Block 64i x 256n, 4 waves n-split, j-step 64, j-split 4.
//   invariant fixed: B(ht) traffic 2.1GB (R1/R2) -> 0.5GB L2->LDS
//   exp built once per (i,j) chip-wide (~20us VALU floor)
//   adjacency HBM stream (268MB ~43us) is the intended wall
// ---------------------------------------------------------------------------

#define LOG2E 1.44269504f

typedef __attribute__((ext_vector_type(8))) short short8;   // 8 bf16 = 4 VGPRs
typedef __attribute__((ext_vector_type(4))) float floatx4;  // MFMA acc

using uint_as1 = __attribute__((address_space(1))) unsigned int;
using uint_as3 = __attribute__((address_space(3))) unsigned int;

__device__ __forceinline__ void gld_lds16(const void* g, void* l) {
  __builtin_amdgcn_global_load_lds((const uint_as1*)g, (uint_as3*)l, 16, 0, 0);
}

__device__ __forceinline__ unsigned short f2b(float f) {  // fp32 -> bf16 RNE (finite)
  unsigned u = __float_as_uint(f);
  u += 0x7fffu + ((u >> 16) & 1u);
  return (unsigned short)(u >> 16);
}
__device__ __forceinline__ float b2f(short s) {
  return __uint_as_float(((unsigned)(unsigned short)s) << 16);
}

// --------------------------- K0a: features -> bf16 -------------------------
__global__ void k_cvt_features(const float* __restrict__ f, unsigned short* __restrict__ fb) {
  int tid = blockIdx.x * 256 + threadIdx.x;
  float4 v = ((const float4*)f)[tid];
  ushort4 o = {f2b(v.x), f2b(v.y), f2b(v.z), f2b(v.w)};
  *(ushort4*)&fb[tid * 4] = o;
}

// ------------------- K0b: W_phi [512][256] -> Wt bf16 [256][512] ------------
__global__ void k_prep_wt(const float* __restrict__ w, unsigned short* __restrict__ wt) {
  int tid = blockIdx.x * 256 + threadIdx.x;
  int n = tid >> 9, k = tid & 511;
  wt[n * 512 + k] = f2b(w[k * 256 + n]);
}

// ----------------- K0c: p_mu = W_phi @ w_mu, p_xi = W_phi @ w_xi ------------
__global__ void k_prep_p(const float* __restrict__ w, const float* __restrict__ wmu,
                         const float* __restrict__ wxi, float* __restrict__ pmu,
                         float* __restrict__ pxi) {
  int tid = blockIdx.x * 256 + threadIdx.x;
  int k = tid >> 2, seg = tid & 3;
  float sm = 0.f, sx = 0.f;
  int base = k * 256 + seg * 64;
#pragma unroll
  for (int c = 0; c < 64; c += 4) {
    float4 wv = *(const float4*)&w[base + c];
    float4 mv = *(const float4*)&wmu[seg * 64 + c];
    float4 xv = *(const float4*)&wxi[seg * 64 + c];
    sm += wv.x * mv.x + wv.y * mv.y + wv.z * mv.z + wv.w * mv.w;
    sx += wv.x * xv.x + wv.y * xv.y + wv.z * xv.z + wv.w * xv.w;
  }
  sm += __shfl_xor(sm, 1); sm += __shfl_xor(sm, 2);
  sx += __shfl_xor(sx, 1); sx += __shfl_xor(sx, 2);
  if (seg == 0) { pmu[k] = sm; pxi[k] = sx; }
}

// --- K2: mu/xi = features_bf @ p_mu / p_xi, PRE-SCALED by log2(e) -----------
__global__ void k_mu_xi(const unsigned short* __restrict__ fb, const float* __restrict__ pmu,
                        const float* __restrict__ pxi, float* __restrict__ mu,
                        float* __restrict__ xi) {
  int w = threadIdx.x >> 6, l = threadIdx.x & 63;
  int i = blockIdx.x * 4 + w;
  short8 fv = *(const short8*)&fb[i * 512 + l * 8];
  float m = 0.f, x = 0.f;
#pragma unroll
  for (int c = 0; c < 8; ++c) {
    float fvf = b2f(fv[c]);
    m = fmaf(fvf, pmu[l * 8 + c], m);
    x = fmaf(fvf, pxi[l * 8 + c], x);
  }
#pragma unroll
  for (int off = 32; off > 0; off >>= 1) {
    m += __shfl_xor(m, off);
    x += __shfl_xor(x, off);
  }
  if (l == 0) { mu[i] = m * LOG2E; xi[i] = x * LOG2E; }
}

// ------------- K1: h_t[n][m] = (features @ W_phi)^T, bf16 MFMA --------------
__global__ __launch_bounds__(256, 2) void k_gemm1(const unsigned short* __restrict__ fb,
                                                  const unsigned short* __restrict__ wt,
                                                  unsigned short* __restrict__ ht) {
  __shared__ __align__(16) unsigned short As[64 * 64];
  __shared__ __align__(16) unsigned short Bs[128 * 64];
  int t = threadIdx.x, w = t >> 6, l = t & 63;
  int bm = blockIdx.x >> 1, bn = blockIdx.x & 1;
  int m0 = bm * 64, n0 = bn * 128;
  int lr = l >> 3, lg = l & 7, g = lg ^ lr;
  int kg = l >> 4, ln = l & 15;
  floatx4 zero = {0.f, 0.f, 0.f, 0.f};
  floatx4 acc[4][2];
#pragma unroll
  for (int mf = 0; mf < 4; ++mf)
#pragma unroll
    for (int nf = 0; nf < 2; ++nf) acc[mf][nf] = zero;

  for (int it = 0; it < 8; ++it) {
    int k0 = it * 64;
#pragma unroll
    for (int q = 0; q < 2; ++q) {
      int row = w * 16 + q * 8 + lr;
      const void* gp = fb + (size_t)(m0 + row) * 512 + k0 + g * 8;
      int lb = __builtin_amdgcn_readfirstlane((w * 16 + q * 8) * 64);
      gld_lds16(gp, &As[lb]);
    }
#pragma unroll
    for (int q = 0; q < 4; ++q) {
      int row = w * 32 + q * 8 + lr;
      const void* gp = wt + (size_t)(n0 + row) * 512 + k0 + g * 8;
      int lb = __builtin_amdgcn_readfirstlane((w * 32 + q * 8) * 64);
      gld_lds16(gp, &Bs[lb]);
    }
    __syncthreads();
#pragma unroll
    for (int ks = 0; ks < 2; ++ks) {
      int gg = ks * 4 + kg;
      int swz = (gg ^ (ln & 7)) * 8;
      short8 bfr[2];
#pragma unroll
      for (int nf = 0; nf < 2; ++nf)
        bfr[nf] = *(const short8*)&Bs[(w * 32 + nf * 16 + ln) * 64 + swz];
#pragma unroll
      for (int mf = 0; mf < 4; ++mf) {
        short8 afr = *(const short8*)&As[(mf * 16 + ln) * 64 + swz];
#pragma unroll
        for (int nf = 0; nf < 2; ++nf)
          acc[mf][nf] = __builtin_amdgcn_mfma_f32_16x16x32_bf16(afr, bfr[nf], acc[mf][nf], 0, 0, 0);
      }
    }
    __syncthreads();
  }
#pragma unroll
  for (int mf = 0; mf < 4; ++mf)
#pragma unroll
    for (int nf = 0; nf < 2; ++nf) {
      int ng = n0 + w * 32 + nf * 16 + ln;
      int mg = m0 + mf * 16 + kg * 4;
      ushort4 o = {f2b(acc[mf][nf][0]), f2b(acc[mf][nf][1]),
                   f2b(acc[mf][nf][2]), f2b(acc[mf][nf][3])};
      *(ushort4*)&ht[(size_t)ng * 8192 + mg] = o;
    }
}

// -------------------- K_zero: clear numerator + Z buffers -------------------
__global__ void k_zero(float* __restrict__ num, float* __restrict__ zbuf) {
  int b = blockIdx.x, t = threadIdx.x;
  if (b < 2048) {
    float4 z4 = {0.f, 0.f, 0.f, 0.f};
    *(float4*)&num[(b * 256 + t) * 4] = z4;
  } else {
    zbuf[(b - 2048) * 256 + t] = 0.f;
  }
}

// --------------------- K3: LDS-pipelined masked attention -------------------
// grid 512 = 4 j-splits x 128 i-blocks (j-major). Block: 64i x 256n, 4 waves
// n-split (wave 64i x 64n, acc 4x4 frags). j-window 2048, j-step 64, 32 iters.
// Bs double-buffered via global_load_lds; Ws single-buffered between barriers.
__global__ __launch_bounds__(256, 2) void k_attn4(const int* __restrict__ adj,
                                                  const unsigned short* __restrict__ ht,
                                                  const float* __restrict__ mu,
                                                  const float* __restrict__ xi,
                                                  float* __restrict__ num,
                                                  float* __restrict__ zbuf) {
  __shared__ __align__(16) unsigned short Bs[2][256 * 64];  // [buf][n][j'] swizzled, 64KB
  __shared__ __align__(16) unsigned short Ws[64 * 64];      // [i][j'] swizzled, 8KB

  int t = threadIdx.x, w = t >> 6, l = t & 63;
  int ln = l & 15, kg = l >> 4;
  int lr = l >> 3, lg = l & 7, g = lg ^ lr;     // staging granule swizzle
  int bi = blockIdx.x & 127, bj = blockIdx.x >> 7;
  int i0 = bi * 64;
  size_t jw = (size_t)bj * 2048;

  // W-build role: thread t owns row wi, 16 j-elems at js
  int wi = t >> 2;
  int js = (t & 3) * 16;
  int g0 = (t & 3) * 2;                          // first granule of this seg
  int p0i = (g0 ^ (wi & 7)) * 8;                 // phys granule offsets (shorts)
  int p1i = ((g0 + 1) ^ (wi & 7)) * 8;
  float mu_s = mu[i0 + wi];                      // pre-scaled by log2e
  const int* arow = adj + (size_t)(i0 + wi) * 8192 + jw + js;
  const float* xrow = xi + jw + js;              // pre-scaled by log2e
  float zacc = 0.f;

  floatx4 zero = {0.f, 0.f, 0.f, 0.f};
  floatx4 acc[4][4];
#pragma unroll
  for (int mf = 0; mf < 4; ++mf)
#pragma unroll
    for (int nf = 0; nf < 4; ++nf) acc[mf][nf] = zero;

  int4 A0, A1, A2, A3;  // adjacency regs for the NEXT tile's W-build
  // ---- prologue: build W(0), stage B(0), prefetch adj(1) ----
  {
    int4 c0 = *(const int4*)(arow + 0);
    int4 c1 = *(const int4*)(arow + 4);
    int4 c2 = *(const int4*)(arow + 8);
    int4 c3 = *(const int4*)(arow + 12);
    float4 x0 = *(const float4*)(xrow + 0);
    float4 x1 = *(const float4*)(xrow + 4);
    float4 x2 = *(const float4*)(xrow + 8);
    float4 x3 = *(const float4*)(xrow + 12);
#pragma unroll
    for (int q = 0; q < 8; ++q) {  // stage B tile 0
      int row = w * 64 + q * 8;
      const void* gp = ht + (size_t)(row + lr) * 8192 + jw + g * 8;
      int lb = __builtin_amdgcn_readfirstlane(row * 64);
      gld_lds16(gp, &Bs[0][lb]);
    }
    A0 = *(const int4*)(arow + 64);
    A1 = *(const int4*)(arow + 68);
    A2 = *(const int4*)(arow + 72);
    A3 = *(const int4*)(arow + 76);
    int am[16] = {c0.x, c0.y, c0.z, c0.w, c1.x, c1.y, c1.z, c1.w,
                  c2.x, c2.y, c2.z, c2.w, c3.x, c3.y, c3.z, c3.w};
    float xv[16] = {x0.x, x0.y, x0.z, x0.w, x1.x, x1.y, x1.z, x1.w,
                    x2.x, x2.y, x2.z, x2.w, x3.x, x3.y, x3.z, x3.w};
    short8 pk0, pk1;
#pragma unroll
    for (int e = 0; e < 16; ++e) {
      float s = mu_s + xv[e];
      s = fmaxf(s, 0.2f * s);
      float ev = __builtin_amdgcn_exp2f(s);
      float wv = (am[e] != 0) ? ev : 0.f;
      zacc += wv;
      if (e < 8) pk0[e] = (short)f2b(wv); else pk1[e - 8] = (short)f2b(wv);
    }
    *(short8*)&Ws[wi * 64 + p0i] = pk0;
    *(short8*)&Ws[wi * 64 + p1i] = pk1;
  }
  __syncthreads();

  // ---- main pipeline: 32 iters, 2 barriers each ----
  for (int c = 0; c < 32; ++c) {
    int buf = c & 1, nb = buf ^ 1;
    float4 x0, x1, x2, x3;
    int4 N0, N1, N2, N3;
    if (c < 31) {
      int jo1 = (c + 1) * 64;
#pragma unroll
      for (int q = 0; q < 8; ++q) {  // stage B(c+1) -> overlaps MFMA(c)
        int row = w * 64 + q * 8;
        const void* gp = ht + (size_t)(row + lr) * 8192 + jw + jo1 + g * 8;
        int lb = __builtin_amdgcn_readfirstlane(nb * (256 * 64) + row * 64);
        gld_lds16(gp, &Bs[0][lb]);
      }
      x0 = *(const float4*)(xrow + jo1);
      x1 = *(const float4*)(xrow + jo1 + 4);
      x2 = *(const float4*)(xrow + jo1 + 8);
      x3 = *(const float4*)(xrow + jo1 + 12);
      int jo2 = (c < 30) ? (c + 2) * 64 : 64;  // wrap harmless
      N0 = *(const int4*)(arow + jo2);
      N1 = *(const int4*)(arow + jo2 + 4);
      N2 = *(const int4*)(arow + jo2 + 8);
      N3 = *(const int4*)(arow + jo2 + 12);
    }
    // --- MFMA tile c: A from Ws, B from Bs[buf] ---
#pragma unroll
    for (int ks = 0; ks < 2; ++ks) {
      int swz = ((ks * 4 + kg) ^ (ln & 7)) * 8;
      short8 af[4], bf[4];
#pragma unroll
      for (int mf = 0; mf < 4; ++mf)
        af[mf] = *(const short8*)&Ws[(mf * 16 + ln) * 64 + swz];
#pragma unroll
      for (int nf = 0; nf < 4; ++nf)
        bf[nf] = *(const short8*)&Bs[buf][(w * 64 + nf * 16 + ln) * 64 + swz];
#pragma unroll
      for (int mf = 0; mf < 4; ++mf)
#pragma unroll
        for (int nf = 0; nf < 4; ++nf)
          acc[mf][nf] = __builtin_amdgcn_mfma_f32_16x16x32_bf16(af[mf], bf[nf], acc[mf][nf], 0, 0, 0);
    }
    __syncthreads();  // #1: all A/B reads of tile c done; staging(c+1) drained
    if (c < 31) {
      int am[16] = {A0.x, A0.y, A0.z, A0.w, A1.x, A1.y, A1.z, A1.w,
                    A2.x, A2.y, A2.z, A2.w, A3.x, A3.y, A3.z, A3.w};
      float xv[16] = {x0.x, x0.y, x0.z, x0.w, x1.x, x1.y, x1.z, x1.w,
                      x2.x, x2.y, x2.z, x2.w, x3.x, x3.y, x3.z, x3.w};
      short8 pk0, pk1;
#pragma unroll
      for (int e = 0; e < 16; ++e) {
        float s = mu_s + xv[e];
        s = fmaxf(s, 0.2f * s);
        float ev = __builtin_amdgcn_exp2f(s);
        float wv = (am[e] != 0) ? ev : 0.f;
        zacc += wv;
        if (e < 8) pk0[e] = (short)f2b(wv); else pk1[e - 8] = (short)f2b(wv);
      }
      *(short8*)&Ws[wi * 64 + p0i] = pk0;
      *(short8*)&Ws[wi * 64 + p1i] = pk1;
      A0 = N0; A1 = N1; A2 = N2; A3 = N3;
    }
    __syncthreads();  // #2: W(c+1) visible
  }

  // ---- Z partial: 4 threads per row ----
  zacc += __shfl_xor(zacc, 1);
  zacc += __shfl_xor(zacc, 2);
  if ((t & 3) == 0) atomicAdd(&zbuf[i0 + wi], zacc);

  // ---- numerator partial -> global atomic accumulate ----
#pragma unroll
  for (int mf = 0; mf < 4; ++mf)
#pragma unroll
    for (int nf = 0; nf < 4; ++nf) {
      int col = w * 64 + nf * 16 + ln;
#pragma unroll
      for (int r = 0; r < 4; ++r) {
        int row = i0 + mf * 16 + kg * 4 + r;
        atomicAdd(&num[(size_t)row * 256 + col], acc[mf][nf][r]);
      }
    }
}

// ------------------------- K4: finalize: /Z then ELU ------------------------
__global__ void k_final(const float* __restrict__ num, const float* __restrict__ zbuf,
                        float* __restrict__ out) {
  int tid = blockIdx.x * 256 + threadIdx.x;  // x4 floats
  int i = tid >> 6;
  float zi = 1.0f / zbuf[i];
  float4 v = *(const float4*)&num[tid * 4];
  v.x *= zi; v.y *= zi; v.z *= zi; v.w *= zi;
  v.x = (v.x > 0.f) ? v.x : (__builtin_amdgcn_exp2f(v.x * LOG2E) - 1.f);
  v.y = (v.y > 0.f) ? v.y : (__builtin_amdgcn_exp2f(v.y * LOG2E) - 1.f);
  v.z = (v.z > 0.f) ? v.z : (__builtin_amdgcn_exp2f(v.z * LOG2E) - 1.f);
  v.w = (v.w > 0.f) ? v.w : (__builtin_amdgcn_exp2f(v.w * LOG2E) - 1.f);
  *(float4*)&out[tid * 4] = v;
}

// ---------------------------------------------------------------------------
extern "C" void kernel_launch(void* const* d_in, const int* in_sizes, int n_in,
                              void* d_out, int out_size, void* d_ws, size_t ws_size,
                              hipStream_t stream) {
  const float* features = (const float*)d_in[0];
  const int* adjm = (const int*)d_in[1];
  const float* W_phi = (const float*)d_in[2];
  const float* w_mu = (const float*)d_in[3];
  const float* w_xi = (const float*)d_in[4];
  float* out = (float*)d_out;

  char* ws = (char*)d_ws;
  unsigned short* fb  = (unsigned short*)(ws + 0);         // 8192x512 bf16 = 8 MB
  unsigned short* ht  = (unsigned short*)(ws + 8388608);   // 256x8192 bf16 = 4 MB
  unsigned short* wt  = (unsigned short*)(ws + 12582912);  // 256x512 bf16 = 256 KB
  float* pmu = (float*)(ws + 12845056);                    // 512 f32
  float* pxi = (float*)(ws + 12847104);                    // 512 f32
  float* muv = (float*)(ws + 12849152);                    // 8192 f32
  float* xiv = (float*)(ws + 12881920);                    // 8192 f32
  // dead-region reuse (after k_gemm1): num over fb, zbuf over wt
  float* num  = (float*)(ws + 0);                          // 8192x256 f32 = 8 MB
  float* zbuf = (float*)(ws + 12582912);                   // 8192 f32

  k_cvt_features<<<4096, 256, 0, stream>>>(features, fb);
  k_prep_wt<<<512, 256, 0, stream>>>(W_phi, wt);
  k_prep_p<<<8, 256, 0, stream>>>(W_phi, w_mu, w_xi, pmu, pxi);
  k_mu_xi<<<2048, 256, 0, stream>>>(fb, pmu, pxi, muv, xiv);
  k_gemm1<<<256, 256, 0, stream>>>(fb, wt, ht);
  k_zero<<<2080, 256, 0, stream>>>(num, zbuf);
  k_attn4<<<512, 256, 0, stream>>>(adjm, ht, muv, xiv, num, zbuf);
  k_final<<<2048, 256, 0, stream>>>(num, zbuf, out);
}